// Round 5
// baseline (609.773 us; speedup 1.0000x reference)
//
#include <hip/hip_runtime.h>
#include <hip/hip_bf16.h>

// MoE SwiGLU FFN, top-2 of 8 experts. B=2,T=2048 -> N=4096 tokens, D=1024, F=4096.
//
//   router    : fp32 logits (exact routing), top-2 + softmax; also x fp32->bf16
//   scan/build: per-expert 128-row padded compaction; tok2row map; 256-row PAIR list
//   tcvt x3   : W1,W3 [E][D][F] -> bf16 [E][F][D]; W2 [E][F][D] -> bf16 [E][D][F]
//   gemm1f    : h = silu(x@W1[e]) * (x@W3[e])  [256-row x 128F x {W1,W3}, 8 waves,
//               4-phase/K-step; ALL prefetch glds at q0; one vmcnt(0) at q3 ->
//               issue-to-wait cover >= 3 phases (the round-4 flaw was q3-issued
//               loads waited at q3 with ~80cy cover)]
//   gemm2f    : y = h @ W2[e]   [BK=64 dbuf, counted-vmcnt pipeline, split-K=2]
//   combine   : out[tok] = w0*(y[r0]+y2[r0]) + w1*(y[r1]+y2[r1])

typedef float f32x4 __attribute__((ext_vector_type(4)));
typedef __bf16 bf16x8 __attribute__((ext_vector_type(8)));

constexpr int N_TOK = 4096;
constexpr int DIM   = 1024;
constexpr int FF    = 4096;
constexpr int NE    = 8;
constexpr int TOPK  = 2;
constexpr int TILE_R = 128;
constexpr int MAXROWS = 9216;             // 8192 + 8*128 padding capacity
constexpr int MAXT    = MAXROWS / TILE_R; // 72
constexpr int MAXP    = 40;               // max 256-row pairs (<= sum ceil(tiles_e/2))

constexpr int BK  = 64;
constexpr int BN1 = 128;                  // gemm1 F-tile (x2 matrices)
constexpr int BN2 = 128;                  // gemm2 D-tile
constexpr int KSPL = 2;                   // gemm2 split-K

// ---- workspace offsets ----
constexpr size_t OFF_TOPI   = 0;          // top_i; rewritten by build -> tok2row
constexpr size_t OFF_TOPW   = 32768;
constexpr size_t OFF_CNT    = 65536;      // counts[8] @ +0, cursor[8] @ +128
constexpr size_t OFF_SEG    = 66048;
constexpr size_t OFF_PTOK   = 67072;
constexpr size_t OFF_SEG2   = 104448;     // pair descriptors (in gap before xb)
constexpr size_t OFF_XBF    = 140800;
constexpr size_t OFF_H      = OFF_XBF + (size_t)N_TOK * DIM * 2;
constexpr size_t OFF_W1T    = OFF_H   + (size_t)MAXROWS * FF * 2;
constexpr size_t OFF_W3T    = OFF_W1T + (size_t)NE * DIM * FF * 2;
constexpr size_t OFF_W2T    = OFF_W3T + (size_t)NE * DIM * FF * 2;
constexpr size_t OFF_Y      = OFF_W1T;    // y  [MAXROWS][DIM] f32 overlays W1T (dead after gemm1)
constexpr size_t OFF_Y2     = OFF_W3T;    // y2 [MAXROWS][DIM] f32 overlays W3T (dead after gemm1)

static __device__ __forceinline__ unsigned short f2bf(float f) {
    unsigned int x = __float_as_uint(f);
    x += 0x7FFFu + ((x >> 16) & 1u);    // round-to-nearest-even
    return (unsigned short)(x >> 16);
}

// async global->LDS, 16B per lane. LDS dest = wave-uniform base + lane*16 (linear);
// global src is per-lane (pre-swizzled for the XOR involution).
#define GLDS16(gsrc, ldst) \
    __builtin_amdgcn_global_load_lds( \
        (const __attribute__((address_space(1))) void*)(gsrc), \
        (__attribute__((address_space(3))) void*)(ldst), 16, 0, 0)

// raw barrier with compiler memory fences on both sides (no vmcnt drain)
static __device__ __forceinline__ void wg_barrier() {
    asm volatile("" ::: "memory");
    __builtin_amdgcn_s_barrier();
    asm volatile("" ::: "memory");
}

// ---------------- router: fp32 logits, top-2, softmax; also writes x bf16 ----------------
__global__ __launch_bounds__(64) void router_kernel(
    const float* __restrict__ x, const float* __restrict__ Wg,
    int* __restrict__ top_i, float* __restrict__ top_w, int* __restrict__ counts,
    unsigned short* __restrict__ xb)
{
    int t = blockIdx.x;
    int lane = threadIdx.x;
    float acc[NE];
#pragma unroll
    for (int e = 0; e < NE; ++e) acc[e] = 0.f;
    const float* xr = x + (size_t)t * DIM;
    unsigned short* xbr = xb + (size_t)t * DIM;
#pragma unroll
    for (int i = 0; i < DIM / 64; ++i) {
        int d = i * 64 + lane;
        float xv = xr[d];
        xbr[d] = f2bf(xv);
        const float4 w0 = *(const float4*)(Wg + (size_t)d * NE);
        const float4 w1 = *(const float4*)(Wg + (size_t)d * NE + 4);
        acc[0] += xv * w0.x; acc[1] += xv * w0.y; acc[2] += xv * w0.z; acc[3] += xv * w0.w;
        acc[4] += xv * w1.x; acc[5] += xv * w1.y; acc[6] += xv * w1.z; acc[7] += xv * w1.w;
    }
#pragma unroll
    for (int s = 32; s > 0; s >>= 1) {
#pragma unroll
        for (int e = 0; e < NE; ++e) acc[e] += __shfl_xor(acc[e], s);
    }
    if (lane == 0) {
        int i0 = 0; float v0 = acc[0];
#pragma unroll
        for (int e = 1; e < NE; ++e) if (acc[e] > v0) { v0 = acc[e]; i0 = e; }
        int i1 = -1; float v1 = -1e30f;
#pragma unroll
        for (int e = 0; e < NE; ++e) if (e != i0 && acc[e] > v1) { v1 = acc[e]; i1 = e; }
        float e1 = expf(v1 - v0);
        float inv = 1.f / (1.f + e1);
        top_i[t * 2 + 0] = i0;  top_i[t * 2 + 1] = i1;
        top_w[t * 2 + 0] = inv; top_w[t * 2 + 1] = e1 * inv;
        atomicAdd(&counts[i0], 1);
        atomicAdd(&counts[i1], 1);
    }
}

// ---------------- scan + tile descriptors (128-tiles for gemm2, 256-pairs for gemm1) ----------------
__global__ void scan_desc_kernel(const int* __restrict__ counts, int* __restrict__ seg,
                                 int* __restrict__ s2)
{
    if (threadIdx.x != 0 || blockIdx.x != 0) return;
    int off = 0, nt = 0, np = 0;
    for (int e = 0; e < NE; ++e) {
        seg[e] = off;
        int c = counts[e];
        int tiles = (c + TILE_R - 1) / TILE_R;
        for (int t = 0; t < tiles; ++t) {
            seg[16 + nt] = e;
            seg[96 + nt] = off + t * TILE_R;
            ++nt;
        }
        for (int t = 0; t < tiles; t += 2) {       // 256-row pairs (same expert)
            s2[8 + np]  = e;
            s2[48 + np] = off + t * TILE_R;
            s2[88 + np] = (t + 1 < tiles) ? off + (t + 1) * TILE_R : off + t * TILE_R;
            ++np;
        }
        off += tiles * TILE_R;
    }
    seg[8] = nt;
    s2[0] = np;
}

// ---------------- build per-expert row lists; top_i becomes tok2row ----------------
__global__ __launch_bounds__(256) void build_kernel(
    int* __restrict__ top_i_rw,
    const int* __restrict__ seg, int* __restrict__ cursor,
    int* __restrict__ pair_tok)
{
    int idx = blockIdx.x * 256 + threadIdx.x;
    if (idx >= N_TOK * TOPK) return;
    int e = top_i_rw[idx];
    int pos = atomicAdd(&cursor[e], 1);
    int row = seg[e] + pos;
    pair_tok[row] = idx >> 1;
    top_i_rw[idx] = row;                  // tok2row (slot-private read-then-write)
}

// ---------------- per-expert transpose + fp32->bf16: src [R][C] -> dst [C][R] ----------------
__global__ __launch_bounds__(256) void tcvt_kernel(
    const float* __restrict__ src, unsigned short* __restrict__ dst, int R, int C)
{
    const float* s = src + (size_t)blockIdx.z * R * C;
    unsigned short* d = dst + (size_t)blockIdx.z * R * C;
    int rt = blockIdx.y * 64, ct = blockIdx.x * 64;
    __shared__ unsigned short L[64][65];

    int t = threadIdx.x;
    int r = t >> 4, c4 = (t & 15) * 4;
#pragma unroll
    for (int i = 0; i < 4; ++i) {
        float4 v = *(const float4*)(s + (size_t)(rt + r + i * 16) * C + ct + c4);
        L[r + i * 16][c4 + 0] = f2bf(v.x);
        L[r + i * 16][c4 + 1] = f2bf(v.y);
        L[r + i * 16][c4 + 2] = f2bf(v.z);
        L[r + i * 16][c4 + 3] = f2bf(v.w);
    }
    __syncthreads();
#pragma unroll
    for (int it = 0; it < 2; ++it) {
        int item = t + it * 256;
        int c  = item >> 3;
        int r8 = (item & 7) * 8;
        unsigned int w0 = (unsigned int)L[r8 + 0][c] | ((unsigned int)L[r8 + 1][c] << 16);
        unsigned int w1 = (unsigned int)L[r8 + 2][c] | ((unsigned int)L[r8 + 3][c] << 16);
        unsigned int w2 = (unsigned int)L[r8 + 4][c] | ((unsigned int)L[r8 + 5][c] << 16);
        unsigned int w3 = (unsigned int)L[r8 + 6][c] | ((unsigned int)L[r8 + 7][c] << 16);
        *(uint4*)(d + (size_t)(ct + c) * R + rt + r8) = make_uint4(w0, w1, w2, w3);
    }
}

// ---------------- gemm1: h = silu(x@W1[e]) * (x@W3[e]) ----------------
// 256-row pair-block x 128 F-cols x {W1,W3}. 512 thr, 8 waves (2M x 4N); per wave
// 128 rows x 32 cols per matrix (acc1+acc3 = 128 VGPR). LDS: 2 x 64KB dbuf
// (A 32K | B1 16K | B3 16K), rows 128B, swizzle (row&7)<<4 both sides.
// 4 phases per K-step. ALL 8 prefetch glds issued at q0 (before q0's ds_reads);
// single vmcnt(0) at q3-end -> every waited load has >=3 phases (~500cy) of cover.
// WAR-safe: nbuf's previous readers retired at K-step t-1's phase barriers.
__global__ __launch_bounds__(512, 2) void gemm1f_kernel(
    const unsigned short* __restrict__ xb, const unsigned short* __restrict__ W1T,
    const unsigned short* __restrict__ W3T,
    const int* __restrict__ pair_tok, const int* __restrict__ s2,
    unsigned short* __restrict__ h)
{
    int p = blockIdx.y;
    if (p >= s2[0]) return;
    int e  = s2[8 + p];
    int rA = s2[48 + p];
    int rB = s2[88 + p];                   // == rA for degenerate (odd) pairs
    int f0 = blockIdx.x * BN1;

    __shared__ __align__(16) char smem[2][65536];   // [buf][A 32K | B1 16K | B3 16K]
    __shared__ int toks[256];

    int tid = threadIdx.x;
    if (tid < 256) {
        int r = (tid < 128) ? rA + tid : rB + tid - 128;
        toks[tid] = pair_tok[r];
    }
    __syncthreads();

    int wid = tid >> 6, lane = tid & 63;
    int wm = wid >> 2, wn = wid & 3;       // 2M x 4N waves
    int lrow = lane & 15;
    int lkb  = (lane >> 4) * 16;           // frag k byte offset
    int axor = (lrow & 7) << 4;            // read-side swizzle

    // staging: per glds, 8 rows x 128B; lane -> row lane>>3, 16B-chunk lane&7.
    int srow8 = lane >> 3;
    int sc = ((((lane & 7) * 16) ^ ((lane >> 3) << 4)) >> 1);  // pre-swizzled src col (elems)

    const unsigned short* aSrc[4];
#pragma unroll
    for (int i = 0; i < 4; ++i) {
        int r = wid * 32 + i * 8 + srow8;              // 0..255
        int tok = toks[r]; if (tok < 0) tok = 0;       // pad rows: output discarded
        aSrc[i] = xb + (size_t)tok * DIM + sc;
    }
    const unsigned short *b1Src[2], *b3Src[2];
#pragma unroll
    for (int j = 0; j < 2; ++j) {
        int fl = f0 + wid * 16 + j * 8 + srow8;        // 0..127 within F-tile
        size_t ro = ((size_t)e * FF + fl) * DIM + sc;
        b1Src[j] = W1T + ro;
        b3Src[j] = W3T + ro;
    }

    f32x4 acc1[8][2], acc3[8][2];
    const f32x4 z4 = {0.f, 0.f, 0.f, 0.f};
#pragma unroll
    for (int m = 0; m < 8; ++m)
#pragma unroll
        for (int n = 0; n < 2; ++n) { acc1[m][n] = z4; acc3[m][n] = z4; }

    // prologue: stage K-step 0 into buf0, drain once
    {
        char* b0 = smem[0];
#pragma unroll
        for (int i = 0; i < 4; ++i)
            GLDS16(aSrc[i], b0 + wid * 4096 + i * 1024);
#pragma unroll
        for (int j = 0; j < 2; ++j) {
            GLDS16(b1Src[j], b0 + 32768 + wid * 2048 + j * 1024);
            GLDS16(b3Src[j], b0 + 49152 + wid * 2048 + j * 1024);
        }
    }
    __syncthreads();

    constexpr int NIT = DIM / BK;          // 16
#pragma unroll 1
    for (int t = 0; t < NIT; ++t) {
        const char* As  = smem[t & 1];
        const char* B1s = smem[t & 1] + 32768;
        const char* B3s = smem[t & 1] + 49152;
        char* nbuf = smem[(t + 1) & 1];
        int k1 = (t + 1) * BK;
        bool pf = (t + 1 < NIT);

#pragma unroll
        for (int q = 0; q < 4; ++q) {
            // --- q0 only: issue the WHOLE next-K-step prefetch (8 glds) first ---
            if (q == 0 && pf) {
#pragma unroll
                for (int i = 0; i < 4; ++i)
                    GLDS16(aSrc[i] + k1, nbuf + wid * 4096 + i * 1024);
#pragma unroll
                for (int j = 0; j < 2; ++j) {
                    GLDS16(b1Src[j] + k1, nbuf + 32768 + wid * 2048 + j * 1024);
                    GLDS16(b3Src[j] + k1, nbuf + 49152 + wid * 2048 + j * 1024);
                }
            }
            // --- phase q: ds-read fragments for m-frags {2q, 2q+1} ---
            bf16x8 a[2][2], b1[2][2], b3[2][2];
#pragma unroll
            for (int kk = 0; kk < 2; ++kk) {
                int kb = kk * 64 + lkb;
#pragma unroll
                for (int mm = 0; mm < 2; ++mm) {
                    int row = wm * 128 + (q * 2 + mm) * 16 + lrow;
                    a[kk][mm] = *(const bf16x8*)(As + row * 128 + (kb ^ axor));
                }
#pragma unroll
                for (int nn = 0; nn < 2; ++nn) {
                    int fl = wn * 32 + nn * 16 + lrow;
                    b1[kk][nn] = *(const bf16x8*)(B1s + fl * 128 + (kb ^ axor));
                    b3[kk][nn] = *(const bf16x8*)(B3s + fl * 128 + (kb ^ axor));
                }
            }
            wg_barrier();
            asm volatile("s_waitcnt lgkmcnt(0)" ::: "memory");
            __builtin_amdgcn_sched_barrier(0);
            __builtin_amdgcn_s_setprio(1);
#pragma unroll
            for (int kk = 0; kk < 2; ++kk)
#pragma unroll
                for (int mm = 0; mm < 2; ++mm)
#pragma unroll
                    for (int nn = 0; nn < 2; ++nn) {
                        acc1[q * 2 + mm][nn] = __builtin_amdgcn_mfma_f32_16x16x32_bf16(
                            a[kk][mm], b1[kk][nn], acc1[q * 2 + mm][nn], 0, 0, 0);
                        acc3[q * 2 + mm][nn] = __builtin_amdgcn_mfma_f32_16x16x32_bf16(
                            a[kk][mm], b3[kk][nn], acc3[q * 2 + mm][nn], 0, 0, 0);
                    }
            __builtin_amdgcn_s_setprio(0);
            if (q == 3)
                asm volatile("s_waitcnt vmcnt(0)" ::: "memory");  // prefetch issued at q0: >=3 phases cover
            wg_barrier();
        }
    }

    // epilogue: silu via v_rcp_f32 (1-ulp approx; absmax budget 6e-3)
    int lj = (lane >> 4) * 4;
#pragma unroll
    for (int m = 0; m < 8; ++m)
#pragma unroll
        for (int n = 0; n < 2; ++n)
#pragma unroll
            for (int j = 0; j < 4; ++j) {
                float h1 = acc1[m][n][j];
                float h3 = acc3[m][n][j];
                float s  = h1 * h3 * __builtin_amdgcn_rcpf(1.f + __expf(-h1));
                int lr  = wm * 128 + m * 16 + lj + j;
                int row = (lr < 128) ? rA + lr : rB + lr - 128;
                int col = f0 + wn * 32 + n * 16 + lrow;
                h[(size_t)row * FF + col] = f2bf(s);
            }
}

// ---------------- gemm2: y(+y2) = h @ W2[e], 128x128, split-K=2, counted-vmcnt dbuf ----------------
// Grid 1152 = 2 khalf x (72 tiles x 8 dblk), XCD-chunked within each khalf.
// Each half reduces K/2=2048 and writes its own f32 partial (y / y2); combine sums.
__global__ __launch_bounds__(256, 2) void gemm2f_kernel(
    const unsigned short* __restrict__ h, const unsigned short* __restrict__ W2T,
    const int* __restrict__ seg, float* __restrict__ y, float* __restrict__ y2)
{
    int bid   = blockIdx.x;
    int khalf = bid / (MAXT * 8);
    int b2    = bid - khalf * (MAXT * 8);
    int x8   = b2 & 7;
    int dblk = (b2 >> 3) & 7;
    int t9   = (b2 >> 3) >> 3;
    int tile = x8 * (MAXT / 8) + t9;
    if (tile >= seg[8]) return;
    int e  = seg[16 + tile];
    int r0 = seg[96 + tile];
    int d0 = dblk * BN2;
    int kbase = khalf * (FF / KSPL);

    __shared__ __align__(16) char smem[2][32768];   // [buf][As 16KB | Bs 16KB]

    int tid = threadIdx.x;
    int wid = tid >> 6, lane = tid & 63;
    int wm = wid >> 1, wn = wid & 1;
    int lrow = lane & 15;
    int lkb  = (lane >> 4) * 16;
    int axor = (lrow & 7) << 4;
    int sc = ((((lane & 7) * 16) ^ ((lane >> 3) << 4)) >> 1);

    const unsigned short* aSrc[4];
#pragma unroll
    for (int i = 0; i < 4; ++i) {
        int r = (wid * 4 + i) * 8 + (lane >> 3);
        aSrc[i] = h + (size_t)(r0 + r) * FF + kbase + sc;
    }
    const unsigned short* bSrc[4];
#pragma unroll
    for (int j = 0; j < 4; ++j) {
        int dl = (wid * 4 + j) * 8 + (lane >> 3);
        bSrc[j] = W2T + ((size_t)e * DIM + d0 + dl) * FF + kbase + sc;
    }

#define STAGE2(buf, koff) { \
    char* AsB = smem[buf]; \
    char* BsB = smem[buf] + 16384; \
    _Pragma("unroll") \
    for (int i = 0; i < 4; ++i) \
        GLDS16(aSrc[i] + (koff), AsB + (wid * 4 + i) * 1024); \
    _Pragma("unroll") \
    for (int j = 0; j < 4; ++j) \
        GLDS16(bSrc[j] + (koff), BsB + (wid * 4 + j) * 1024); }

    f32x4 acc[4][4];
    const f32x4 z4 = {0.f, 0.f, 0.f, 0.f};
#pragma unroll
    for (int m = 0; m < 4; ++m)
#pragma unroll
        for (int n = 0; n < 4; ++n) acc[m][n] = z4;

    constexpr int NIT = (FF / KSPL) / BK;  // 32
    STAGE2(0, 0);
    int cur = 0;
    for (int it = 0; it < NIT; ++it) {
        if (it + 1 < NIT) {
            STAGE2(cur ^ 1, (it + 1) * BK);    // prefetch next K-step (8 loads)
            asm volatile("s_waitcnt vmcnt(8)" ::: "memory");  // cur staged; prefetch in flight
        } else {
            asm volatile("s_waitcnt vmcnt(0)" ::: "memory");
        }
        wg_barrier();                          // barrier 1: buf cur staged by ALL waves

        const char* AsR = smem[cur];
        const char* BsR = smem[cur] + 16384;
        bf16x8 a[2][4], b[2][4];
#pragma unroll
        for (int kk = 0; kk < 2; ++kk) {
            int kb = kk * 64 + lkb;
#pragma unroll
            for (int m = 0; m < 4; ++m) {
                int row = wm * 64 + m * 16 + lrow;
                a[kk][m] = *(const bf16x8*)(AsR + row * 128 + (kb ^ axor));
            }
#pragma unroll
            for (int n = 0; n < 4; ++n) {
                int row = wn * 64 + n * 16 + lrow;
                b[kk][n] = *(const bf16x8*)(BsR + row * 128 + (kb ^ axor));
            }
        }
        asm volatile("s_waitcnt lgkmcnt(0)" ::: "memory");
        wg_barrier();                          // barrier 2: reads retired; cur overwritable

#pragma unroll
        for (int kk = 0; kk < 2; ++kk)
#pragma unroll
            for (int m = 0; m < 4; ++m)
#pragma unroll
                for (int n = 0; n < 4; ++n)
                    acc[m][n] = __builtin_amdgcn_mfma_f32_16x16x32_bf16(a[kk][m], b[kk][n], acc[m][n], 0, 0, 0);
        cur ^= 1;
    }
#undef STAGE2

    // epilogue: direct scattered f32 stores (64B per 16-lane group)
    float* yt = khalf ? y2 : y;
    int lj = (lane >> 4) * 4;
#pragma unroll
    for (int m = 0; m < 4; ++m)
#pragma unroll
        for (int n = 0; n < 4; ++n)
#pragma unroll
            for (int j = 0; j < 4; ++j) {
                int row = r0 + wm * 64 + m * 16 + lj + j;     // pad rows: never combined
                int col = d0 + wn * 64 + n * 16 + lrow;
                yt[(size_t)row * DIM + col] = acc[m][n][j];
            }
}

// ---------------- combine: out[tok] = w0*(y[r0]+y2[r0]) + w1*(y[r1]+y2[r1]) ----------------
__global__ __launch_bounds__(256) void combine_kernel(
    const float* __restrict__ y, const float* __restrict__ y2,
    const int* __restrict__ tok2row,
    const float* __restrict__ top_w, float* __restrict__ out)
{
    int t = blockIdx.x;
    int c = threadIdx.x * 4;
    int r0 = tok2row[t * 2], r1 = tok2row[t * 2 + 1];
    float w0 = top_w[t * 2], w1 = top_w[t * 2 + 1];
    float4 a0 = *(const float4*)(y  + (size_t)r0 * DIM + c);
    float4 a1 = *(const float4*)(y2 + (size_t)r0 * DIM + c);
    float4 b0 = *(const float4*)(y  + (size_t)r1 * DIM + c);
    float4 b1 = *(const float4*)(y2 + (size_t)r1 * DIM + c);
    float4 o;
    o.x = w0 * (a0.x + a1.x) + w1 * (b0.x + b1.x);
    o.y = w0 * (a0.y + a1.y) + w1 * (b0.y + b1.y);
    o.z = w0 * (a0.z + a1.z) + w1 * (b0.z + b1.z);
    o.w = w0 * (a0.w + a1.w) + w1 * (b0.w + b1.w);
    *(float4*)(out + (size_t)t * DIM + c) = o;
}

extern "C" void kernel_launch(void* const* d_in, const int* in_sizes, int n_in,
                              void* d_out, int out_size, void* d_ws, size_t ws_size,
                              hipStream_t stream)
{
    const float* x  = (const float*)d_in[0];
    const float* Wg = (const float*)d_in[1];
    const float* W1 = (const float*)d_in[2];
    const float* W3 = (const float*)d_in[3];
    const float* W2 = (const float*)d_in[4];
    float* out = (float*)d_out;

    char* ws = (char*)d_ws;
    int*   top_i    = (int*)(ws + OFF_TOPI);   // becomes tok2row after build
    float* top_w    = (float*)(ws + OFF_TOPW);
    int*   counts   = (int*)(ws + OFF_CNT);
    int*   cursor   = (int*)(ws + OFF_CNT + 128);
    int*   seg      = (int*)(ws + OFF_SEG);
    int*   pair_tok = (int*)(ws + OFF_PTOK);
    int*   s2       = (int*)(ws + OFF_SEG2);
    unsigned short* xb  = (unsigned short*)(ws + OFF_XBF);
    unsigned short* h   = (unsigned short*)(ws + OFF_H);
    unsigned short* W1T = (unsigned short*)(ws + OFF_W1T);
    unsigned short* W3T = (unsigned short*)(ws + OFF_W3T);
    unsigned short* W2T = (unsigned short*)(ws + OFF_W2T);
    float* y  = (float*)(ws + OFF_Y);
    float* y2 = (float*)(ws + OFF_Y2);

    hipMemsetAsync(counts, 0, 512, stream);
    hipMemsetAsync(pair_tok, 0xFF, MAXROWS * sizeof(int), stream);

    router_kernel<<<N_TOK, 64, 0, stream>>>(x, Wg, top_i, top_w, counts, xb);
    scan_desc_kernel<<<1, 64, 0, stream>>>(counts, seg, s2);
    build_kernel<<<(N_TOK * TOPK + 255) / 256, 256, 0, stream>>>(top_i, seg, cursor, pair_tok);

    dim3 gt13(FF / 64, DIM / 64, NE);
    tcvt_kernel<<<gt13, 256, 0, stream>>>(W1, W1T, DIM, FF);
    tcvt_kernel<<<gt13, 256, 0, stream>>>(W3, W3T, DIM, FF);
    dim3 gt2(DIM / 64, FF / 64, NE);
    tcvt_kernel<<<gt2, 256, 0, stream>>>(W2, W2T, FF, DIM);

    dim3 g1(FF / BN1, MAXP);
    gemm1f_kernel<<<g1, 512, 0, stream>>>(xb, W1T, W3T, pair_tok, s2, h);
    gemm2f_kernel<<<MAXT * 8 * KSPL, 256, 0, stream>>>(h, W2T, seg, y, y2);
    combine_kernel<<<N_TOK, 256, 0, stream>>>(y, y2, top_i, top_w, out);
}

// Round 6
// 526.090 us; speedup vs baseline: 1.1591x; 1.1591x over previous
//
#include <hip/hip_runtime.h>
#include <hip/hip_bf16.h>

// MoE SwiGLU FFN, top-2 of 8 experts. B=2,T=2048 -> N=4096 tokens, D=1024, F=4096.
//
//   router    : fp32 logits (exact routing), top-2 + softmax; also x fp32->bf16
//               [4 tokens/block, 1 wave each]
//   scan/build: per-expert 128-row padded compaction; tok2row map (aliases top_i)
//   tcvt      : W1+W3 merged launch [E][D][F] -> bf16 [E][F][D]; W2 separate
//   gemm1f    : h = silu(x@W1[e]) * (x@W3[e])   [256 thr, 128x128, 2-barrier loop]
//   gemm2f    : y = h @ W2[e]   [BK=64 dbuf, counted-vmcnt pipeline, split-K=2]
//   combine   : out[tok] = w0*(y[r0]+y2[r0]) + w1*(y[r1]+y2[r1])
//
// NOTE (rounds 1/2/4/5): all deep-pipeline variants of gemm1 (BK=32 dbuf,
// counted-vmcnt 2-phase, 256-row 4-phase w/ either prefetch placement) REGRESSED
// (237/318/224/270 us vs 185 here). The dual-B SwiGLU GEMM is LDS-read-bound per
// phase (12 ds_read_b128/wave/phase), so multi-barrier schedules serialize worse
// than the compiler's 2-barrier loop + 2-blocks/CU overlap. Do not retry without
// changing the read-volume:MFMA ratio.

typedef float f32x4 __attribute__((ext_vector_type(4)));
typedef __bf16 bf16x8 __attribute__((ext_vector_type(8)));

constexpr int N_TOK = 4096;
constexpr int DIM   = 1024;
constexpr int FF    = 4096;
constexpr int NE    = 8;
constexpr int TOPK  = 2;
constexpr int TILE_R = 128;
constexpr int MAXROWS = 9216;             // 8192 + 8*128 padding capacity
constexpr int MAXT    = MAXROWS / TILE_R; // 72

constexpr int BK  = 64;
constexpr int BN1 = 128;                  // gemm1 F-tile
constexpr int BN2 = 128;                  // gemm2 D-tile
constexpr int KSPL = 2;                   // gemm2 split-K

// ---- workspace offsets ----
constexpr size_t OFF_TOPI   = 0;          // top_i; rewritten by build -> tok2row
constexpr size_t OFF_TOPW   = 32768;
constexpr size_t OFF_CNT    = 65536;      // counts[8] @ +0, cursor[8] @ +128
constexpr size_t OFF_SEG    = 66048;
constexpr size_t OFF_PTOK   = 67072;
constexpr size_t OFF_XBF    = 140800;
constexpr size_t OFF_H      = OFF_XBF + (size_t)N_TOK * DIM * 2;
constexpr size_t OFF_W1T    = OFF_H   + (size_t)MAXROWS * FF * 2;
constexpr size_t OFF_W3T    = OFF_W1T + (size_t)NE * DIM * FF * 2;
constexpr size_t OFF_W2T    = OFF_W3T + (size_t)NE * DIM * FF * 2;
constexpr size_t OFF_Y      = OFF_W1T;    // y  [MAXROWS][DIM] f32 overlays W1T (dead after gemm1)
constexpr size_t OFF_Y2     = OFF_W3T;    // y2 [MAXROWS][DIM] f32 overlays W3T (dead after gemm1)

static __device__ __forceinline__ unsigned short f2bf(float f) {
    unsigned int x = __float_as_uint(f);
    x += 0x7FFFu + ((x >> 16) & 1u);    // round-to-nearest-even
    return (unsigned short)(x >> 16);
}

// async global->LDS, 16B per lane. LDS dest = wave-uniform base + lane*16 (linear);
// global src is per-lane (pre-swizzled for the XOR involution).
#define GLDS16(gsrc, ldst) \
    __builtin_amdgcn_global_load_lds( \
        (const __attribute__((address_space(1))) void*)(gsrc), \
        (__attribute__((address_space(3))) void*)(ldst), 16, 0, 0)

// raw barrier with compiler memory fences on both sides (no vmcnt drain)
static __device__ __forceinline__ void wg_barrier() {
    asm volatile("" ::: "memory");
    __builtin_amdgcn_s_barrier();
    asm volatile("" ::: "memory");
}

// ---------------- router: 4 tokens/block (1 wave each); fp32 logits, top-2, softmax ----------------
__global__ __launch_bounds__(256) void router_kernel(
    const float* __restrict__ x, const float* __restrict__ Wg,
    int* __restrict__ top_i, float* __restrict__ top_w, int* __restrict__ counts,
    unsigned short* __restrict__ xb)
{
    int t = blockIdx.x * 4 + (threadIdx.x >> 6);
    int lane = threadIdx.x & 63;
    float acc[NE];
#pragma unroll
    for (int e = 0; e < NE; ++e) acc[e] = 0.f;
    const float* xr = x + (size_t)t * DIM;
    unsigned short* xbr = xb + (size_t)t * DIM;
#pragma unroll
    for (int i = 0; i < DIM / 64; ++i) {
        int d = i * 64 + lane;
        float xv = xr[d];
        xbr[d] = f2bf(xv);
        const float4 w0 = *(const float4*)(Wg + (size_t)d * NE);
        const float4 w1 = *(const float4*)(Wg + (size_t)d * NE + 4);
        acc[0] += xv * w0.x; acc[1] += xv * w0.y; acc[2] += xv * w0.z; acc[3] += xv * w0.w;
        acc[4] += xv * w1.x; acc[5] += xv * w1.y; acc[6] += xv * w1.z; acc[7] += xv * w1.w;
    }
#pragma unroll
    for (int s = 32; s > 0; s >>= 1) {
#pragma unroll
        for (int e = 0; e < NE; ++e) acc[e] += __shfl_xor(acc[e], s);
    }
    if (lane == 0) {
        int i0 = 0; float v0 = acc[0];
#pragma unroll
        for (int e = 1; e < NE; ++e) if (acc[e] > v0) { v0 = acc[e]; i0 = e; }
        int i1 = -1; float v1 = -1e30f;
#pragma unroll
        for (int e = 0; e < NE; ++e) if (e != i0 && acc[e] > v1) { v1 = acc[e]; i1 = e; }
        float e1 = expf(v1 - v0);
        float inv = 1.f / (1.f + e1);
        top_i[t * 2 + 0] = i0;  top_i[t * 2 + 1] = i1;
        top_w[t * 2 + 0] = inv; top_w[t * 2 + 1] = e1 * inv;
        atomicAdd(&counts[i0], 1);
        atomicAdd(&counts[i1], 1);
    }
}

// ---------------- scan + tile descriptors ----------------
__global__ void scan_desc_kernel(const int* __restrict__ counts, int* __restrict__ seg)
{
    if (threadIdx.x != 0 || blockIdx.x != 0) return;
    int off = 0, nt = 0;
    for (int e = 0; e < NE; ++e) {
        seg[e] = off;
        int c = counts[e];
        int tiles = (c + TILE_R - 1) / TILE_R;
        for (int t = 0; t < tiles; ++t) {
            seg[16 + nt] = e;
            seg[96 + nt] = off + t * TILE_R;
            ++nt;
        }
        off += tiles * TILE_R;
    }
    seg[8] = nt;
}

// ---------------- build per-expert row lists; top_i becomes tok2row ----------------
__global__ __launch_bounds__(256) void build_kernel(
    int* __restrict__ top_i_rw,
    const int* __restrict__ seg, int* __restrict__ cursor,
    int* __restrict__ pair_tok)
{
    int idx = blockIdx.x * 256 + threadIdx.x;
    if (idx >= N_TOK * TOPK) return;
    int e = top_i_rw[idx];
    int pos = atomicAdd(&cursor[e], 1);
    int row = seg[e] + pos;
    pair_tok[row] = idx >> 1;
    top_i_rw[idx] = row;                  // tok2row (slot-private read-then-write)
}

// ---------------- per-expert transpose + fp32->bf16: src [R][C] -> dst [C][R] ----------------
// z in [0,16): z<8 -> W1 expert z; z>=8 -> W3 expert z-8 (merged launch).
__global__ __launch_bounds__(256) void tcvt13_kernel(
    const float* __restrict__ s1, const float* __restrict__ s3,
    unsigned short* __restrict__ d1, unsigned short* __restrict__ d3)
{
    constexpr int R = DIM, C = FF;
    int z = blockIdx.z;
    const float* s = ((z < NE) ? s1 : s3) + (size_t)(z & 7) * R * C;
    unsigned short* d = ((z < NE) ? d1 : d3) + (size_t)(z & 7) * R * C;
    int rt = blockIdx.y * 64, ct = blockIdx.x * 64;
    __shared__ unsigned short L[64][65];

    int t = threadIdx.x;
    int r = t >> 4, c4 = (t & 15) * 4;
#pragma unroll
    for (int i = 0; i < 4; ++i) {
        float4 v = *(const float4*)(s + (size_t)(rt + r + i * 16) * C + ct + c4);
        L[r + i * 16][c4 + 0] = f2bf(v.x);
        L[r + i * 16][c4 + 1] = f2bf(v.y);
        L[r + i * 16][c4 + 2] = f2bf(v.z);
        L[r + i * 16][c4 + 3] = f2bf(v.w);
    }
    __syncthreads();
#pragma unroll
    for (int it = 0; it < 2; ++it) {
        int item = t + it * 256;
        int c  = item >> 3;
        int r8 = (item & 7) * 8;
        unsigned int w0 = (unsigned int)L[r8 + 0][c] | ((unsigned int)L[r8 + 1][c] << 16);
        unsigned int w1 = (unsigned int)L[r8 + 2][c] | ((unsigned int)L[r8 + 3][c] << 16);
        unsigned int w2 = (unsigned int)L[r8 + 4][c] | ((unsigned int)L[r8 + 5][c] << 16);
        unsigned int w3 = (unsigned int)L[r8 + 6][c] | ((unsigned int)L[r8 + 7][c] << 16);
        *(uint4*)(d + (size_t)(ct + c) * R + rt + r8) = make_uint4(w0, w1, w2, w3);
    }
}

__global__ __launch_bounds__(256) void tcvt_kernel(
    const float* __restrict__ src, unsigned short* __restrict__ dst, int R, int C)
{
    const float* s = src + (size_t)blockIdx.z * R * C;
    unsigned short* d = dst + (size_t)blockIdx.z * R * C;
    int rt = blockIdx.y * 64, ct = blockIdx.x * 64;
    __shared__ unsigned short L[64][65];

    int t = threadIdx.x;
    int r = t >> 4, c4 = (t & 15) * 4;
#pragma unroll
    for (int i = 0; i < 4; ++i) {
        float4 v = *(const float4*)(s + (size_t)(rt + r + i * 16) * C + ct + c4);
        L[r + i * 16][c4 + 0] = f2bf(v.x);
        L[r + i * 16][c4 + 1] = f2bf(v.y);
        L[r + i * 16][c4 + 2] = f2bf(v.z);
        L[r + i * 16][c4 + 3] = f2bf(v.w);
    }
    __syncthreads();
#pragma unroll
    for (int it = 0; it < 2; ++it) {
        int item = t + it * 256;
        int c  = item >> 3;
        int r8 = (item & 7) * 8;
        unsigned int w0 = (unsigned int)L[r8 + 0][c] | ((unsigned int)L[r8 + 1][c] << 16);
        unsigned int w1 = (unsigned int)L[r8 + 2][c] | ((unsigned int)L[r8 + 3][c] << 16);
        unsigned int w2 = (unsigned int)L[r8 + 4][c] | ((unsigned int)L[r8 + 5][c] << 16);
        unsigned int w3 = (unsigned int)L[r8 + 6][c] | ((unsigned int)L[r8 + 7][c] << 16);
        *(uint4*)(d + (size_t)(ct + c) * R + rt + r8) = make_uint4(w0, w1, w2, w3);
    }
}

// ---------------- gemm1: h = silu(x@W1[e]) * (x@W3[e]), 128x128, 256 thr ----------------
// Proven structure: single-buffer BK=64, 2 barriers/K-step; compiler interleaves
// ds_read/MFMA with fine lgkmcnt; 2 blocks/CU hide the barrier drain.
// Physical col-byte = logical ^ ((row&7)<<4), applied on glds SOURCE and ds_read.
__global__ __launch_bounds__(256, 2) void gemm1f_kernel(
    const unsigned short* __restrict__ xb, const unsigned short* __restrict__ W1T,
    const unsigned short* __restrict__ W3T,
    const int* __restrict__ pair_tok, const int* __restrict__ seg,
    unsigned short* __restrict__ h)
{
    int tile = blockIdx.y;
    if (tile >= seg[8]) return;
    int e  = seg[16 + tile];
    int r0 = seg[96 + tile];
    int f0 = blockIdx.x * BN1;

    __shared__ unsigned short As[TILE_R * BK];   // 16 KB (16 chunks of 8 rows x 128B)
    __shared__ unsigned short B1s[BN1 * BK];     // 16 KB
    __shared__ unsigned short B3s[BN1 * BK];     // 16 KB
    __shared__ int toks[TILE_R];

    int tid = threadIdx.x;
    if (tid < TILE_R) toks[tid] = pair_tok[r0 + tid];
    __syncthreads();

    int wid = tid >> 6, lane = tid & 63;
    int wm = wid >> 1, wn = wid & 1;             // 2x2 waves, each 64x64 per B
    int lrow = lane & 15;
    int lkb  = (lane >> 4) * 16;                 // frag k byte offset
    int axor = (lrow & 7) << 4;                  // read-side swizzle

    // pre-swizzled source col (elements) for glds staging:
    int sc = ((((lane & 7) * 16) ^ ((lane >> 3) << 4)) >> 1);

    const unsigned short* aSrc[4];
#pragma unroll
    for (int i = 0; i < 4; ++i) {
        int r = (wid * 4 + i) * 8 + (lane >> 3);
        int tok = toks[r]; if (tok < 0) tok = 0;   // pad rows: output discarded
        aSrc[i] = xb + (size_t)tok * DIM + sc;
    }
    const unsigned short *b1Src[4], *b3Src[4];
#pragma unroll
    for (int j = 0; j < 4; ++j) {
        int fl = (wid * 4 + j) * 8 + (lane >> 3);
        size_t rowoff = ((size_t)e * FF + f0 + fl) * DIM + sc;
        b1Src[j] = W1T + rowoff;
        b3Src[j] = W3T + rowoff;
    }

    f32x4 acc1[4][4], acc3[4][4];
    const f32x4 z4 = {0.f, 0.f, 0.f, 0.f};
#pragma unroll
    for (int m = 0; m < 4; ++m)
#pragma unroll
        for (int n = 0; n < 4; ++n) { acc1[m][n] = z4; acc3[m][n] = z4; }

    for (int k0 = 0; k0 < DIM; k0 += BK) {
#pragma unroll
        for (int i = 0; i < 4; ++i)
            GLDS16(aSrc[i] + k0, (char*)As + (wid * 4 + i) * 1024);
#pragma unroll
        for (int j = 0; j < 4; ++j) {
            GLDS16(b1Src[j] + k0, (char*)B1s + (wid * 4 + j) * 1024);
            GLDS16(b3Src[j] + k0, (char*)B3s + (wid * 4 + j) * 1024);
        }
        __syncthreads();   // drains vmcnt (glds) + barrier

#pragma unroll
        for (int kk = 0; kk < 2; ++kk) {
            int kb = kk * 64 + lkb;
            bf16x8 a[4], b1[4], b3[4];
#pragma unroll
            for (int m = 0; m < 4; ++m) {
                int row = wm * 64 + m * 16 + lrow;
                a[m] = *(const bf16x8*)((const char*)As + row * 128 + (kb ^ axor));
            }
#pragma unroll
            for (int n = 0; n < 4; ++n) {
                int row = wn * 64 + n * 16 + lrow;
                b1[n] = *(const bf16x8*)((const char*)B1s + row * 128 + (kb ^ axor));
                b3[n] = *(const bf16x8*)((const char*)B3s + row * 128 + (kb ^ axor));
            }
#pragma unroll
            for (int m = 0; m < 4; ++m)
#pragma unroll
                for (int n = 0; n < 4; ++n) {
                    acc1[m][n] = __builtin_amdgcn_mfma_f32_16x16x32_bf16(a[m], b1[n], acc1[m][n], 0, 0, 0);
                    acc3[m][n] = __builtin_amdgcn_mfma_f32_16x16x32_bf16(a[m], b3[n], acc3[m][n], 0, 0, 0);
                }
        }
        __syncthreads();
    }

    // epilogue: silu via v_rcp_f32 (1-ulp approx; absmax budget 6e-3)
    int lj = (lane >> 4) * 4;
#pragma unroll
    for (int m = 0; m < 4; ++m)
#pragma unroll
        for (int n = 0; n < 4; ++n)
#pragma unroll
            for (int j = 0; j < 4; ++j) {
                float h1 = acc1[m][n][j];
                float h3 = acc3[m][n][j];
                float s  = h1 * h3 * __builtin_amdgcn_rcpf(1.f + __expf(-h1));
                int row = r0 + wm * 64 + m * 16 + lj + j;
                int col = f0 + wn * 64 + n * 16 + lrow;
                h[(size_t)row * FF + col] = f2bf(s);
            }
}

// ---------------- gemm2: y(+y2) = h @ W2[e], 128x128, split-K=2, counted-vmcnt dbuf ----------------
// Grid 1152 = 2 khalf x (72 tiles x 8 dblk), XCD-chunked within each khalf.
// Each half reduces K/2=2048 and writes its own f32 partial (y / y2); combine sums.
__global__ __launch_bounds__(256, 2) void gemm2f_kernel(
    const unsigned short* __restrict__ h, const unsigned short* __restrict__ W2T,
    const int* __restrict__ seg, float* __restrict__ y, float* __restrict__ y2)
{
    int bid   = blockIdx.x;
    int khalf = bid / (MAXT * 8);
    int b2    = bid - khalf * (MAXT * 8);
    int x8   = b2 & 7;
    int dblk = (b2 >> 3) & 7;
    int t9   = (b2 >> 3) >> 3;
    int tile = x8 * (MAXT / 8) + t9;
    if (tile >= seg[8]) return;
    int e  = seg[16 + tile];
    int r0 = seg[96 + tile];
    int d0 = dblk * BN2;
    int kbase = khalf * (FF / KSPL);

    __shared__ __align__(16) char smem[2][32768];   // [buf][As 16KB | Bs 16KB]

    int tid = threadIdx.x;
    int wid = tid >> 6, lane = tid & 63;
    int wm = wid >> 1, wn = wid & 1;
    int lrow = lane & 15;
    int lkb  = (lane >> 4) * 16;
    int axor = (lrow & 7) << 4;
    int sc = ((((lane & 7) * 16) ^ ((lane >> 3) << 4)) >> 1);

    const unsigned short* aSrc[4];
#pragma unroll
    for (int i = 0; i < 4; ++i) {
        int r = (wid * 4 + i) * 8 + (lane >> 3);
        aSrc[i] = h + (size_t)(r0 + r) * FF + kbase + sc;
    }
    const unsigned short* bSrc[4];
#pragma unroll
    for (int j = 0; j < 4; ++j) {
        int dl = (wid * 4 + j) * 8 + (lane >> 3);
        bSrc[j] = W2T + ((size_t)e * DIM + d0 + dl) * FF + kbase + sc;
    }

#define STAGE2(buf, koff) { \
    char* AsB = smem[buf]; \
    char* BsB = smem[buf] + 16384; \
    _Pragma("unroll") \
    for (int i = 0; i < 4; ++i) \
        GLDS16(aSrc[i] + (koff), AsB + (wid * 4 + i) * 1024); \
    _Pragma("unroll") \
    for (int j = 0; j < 4; ++j) \
        GLDS16(bSrc[j] + (koff), BsB + (wid * 4 + j) * 1024); }

    f32x4 acc[4][4];
    const f32x4 z4 = {0.f, 0.f, 0.f, 0.f};
#pragma unroll
    for (int m = 0; m < 4; ++m)
#pragma unroll
        for (int n = 0; n < 4; ++n) acc[m][n] = z4;

    constexpr int NIT = (FF / KSPL) / BK;  // 32
    STAGE2(0, 0);
    int cur = 0;
    for (int it = 0; it < NIT; ++it) {
        if (it + 1 < NIT) {
            STAGE2(cur ^ 1, (it + 1) * BK);    // prefetch next K-step (8 loads)
            asm volatile("s_waitcnt vmcnt(8)" ::: "memory");  // cur staged; prefetch in flight
        } else {
            asm volatile("s_waitcnt vmcnt(0)" ::: "memory");
        }
        wg_barrier();                          // barrier 1: buf cur staged by ALL waves

        const char* AsR = smem[cur];
        const char* BsR = smem[cur] + 16384;
        bf16x8 a[2][4], b[2][4];
#pragma unroll
        for (int kk = 0; kk < 2; ++kk) {
            int kb = kk * 64 + lkb;
#pragma unroll
            for (int m = 0; m < 4; ++m) {
                int row = wm * 64 + m * 16 + lrow;
                a[kk][m] = *(const bf16x8*)(AsR + row * 128 + (kb ^ axor));
            }
#pragma unroll
            for (int n = 0; n < 4; ++n) {
                int row = wn * 64 + n * 16 + lrow;
                b[kk][n] = *(const bf16x8*)(BsR + row * 128 + (kb ^ axor));
            }
        }
        asm volatile("s_waitcnt lgkmcnt(0)" ::: "memory");
        wg_barrier();                          // barrier 2: reads retired; cur overwritable

#pragma unroll
        for (int kk = 0; kk < 2; ++kk)
#pragma unroll
            for (int m = 0; m < 4; ++m)
#pragma unroll
                for (int n = 0; n < 4; ++n)
                    acc[m][n] = __builtin_amdgcn_mfma_f32_16x16x32_bf16(a[kk][m], b[kk][n], acc[m][n], 0, 0, 0);
        cur ^= 1;
    }
#undef STAGE2

    // epilogue: direct scattered f32 stores (64B per 16-lane group)
    float* yt = khalf ? y2 : y;
    int lj = (lane >> 4) * 4;
#pragma unroll
    for (int m = 0; m < 4; ++m)
#pragma unroll
        for (int n = 0; n < 4; ++n)
#pragma unroll
            for (int j = 0; j < 4; ++j) {
                int row = r0 + wm * 64 + m * 16 + lj + j;     // pad rows: never combined
                int col = d0 + wn * 64 + n * 16 + lrow;
                yt[(size_t)row * DIM + col] = acc[m][n][j];
            }
}

// ---------------- combine: out[tok] = w0*(y[r0]+y2[r0]) + w1*(y[r1]+y2[r1]) ----------------
__global__ __launch_bounds__(256) void combine_kernel(
    const float* __restrict__ y, const float* __restrict__ y2,
    const int* __restrict__ tok2row,
    const float* __restrict__ top_w, float* __restrict__ out)
{
    int t = blockIdx.x;
    int c = threadIdx.x * 4;
    int r0 = tok2row[t * 2], r1 = tok2row[t * 2 + 1];
    float w0 = top_w[t * 2], w1 = top_w[t * 2 + 1];
    float4 a0 = *(const float4*)(y  + (size_t)r0 * DIM + c);
    float4 a1 = *(const float4*)(y2 + (size_t)r0 * DIM + c);
    float4 b0 = *(const float4*)(y  + (size_t)r1 * DIM + c);
    float4 b1 = *(const float4*)(y2 + (size_t)r1 * DIM + c);
    float4 o;
    o.x = w0 * (a0.x + a1.x) + w1 * (b0.x + b1.x);
    o.y = w0 * (a0.y + a1.y) + w1 * (b0.y + b1.y);
    o.z = w0 * (a0.z + a1.z) + w1 * (b0.z + b1.z);
    o.w = w0 * (a0.w + a1.w) + w1 * (b0.w + b1.w);
    *(float4*)(out + (size_t)t * DIM + c) = o;
}

extern "C" void kernel_launch(void* const* d_in, const int* in_sizes, int n_in,
                              void* d_out, int out_size, void* d_ws, size_t ws_size,
                              hipStream_t stream)
{
    const float* x  = (const float*)d_in[0];
    const float* Wg = (const float*)d_in[1];
    const float* W1 = (const float*)d_in[2];
    const float* W3 = (const float*)d_in[3];
    const float* W2 = (const float*)d_in[4];
    float* out = (float*)d_out;

    char* ws = (char*)d_ws;
    int*   top_i    = (int*)(ws + OFF_TOPI);   // becomes tok2row after build
    float* top_w    = (float*)(ws + OFF_TOPW);
    int*   counts   = (int*)(ws + OFF_CNT);
    int*   cursor   = (int*)(ws + OFF_CNT + 128);
    int*   seg      = (int*)(ws + OFF_SEG);
    int*   pair_tok = (int*)(ws + OFF_PTOK);
    unsigned short* xb  = (unsigned short*)(ws + OFF_XBF);
    unsigned short* h   = (unsigned short*)(ws + OFF_H);
    unsigned short* W1T = (unsigned short*)(ws + OFF_W1T);
    unsigned short* W3T = (unsigned short*)(ws + OFF_W3T);
    unsigned short* W2T = (unsigned short*)(ws + OFF_W2T);
    float* y  = (float*)(ws + OFF_Y);
    float* y2 = (float*)(ws + OFF_Y2);

    hipMemsetAsync(counts, 0, 512, stream);
    hipMemsetAsync(pair_tok, 0xFF, MAXROWS * sizeof(int), stream);

    router_kernel<<<N_TOK / 4, 256, 0, stream>>>(x, Wg, top_i, top_w, counts, xb);
    scan_desc_kernel<<<1, 64, 0, stream>>>(counts, seg);
    build_kernel<<<(N_TOK * TOPK + 255) / 256, 256, 0, stream>>>(top_i, seg, cursor, pair_tok);

    dim3 gt13(FF / 64, DIM / 64, NE * 2);
    tcvt13_kernel<<<gt13, 256, 0, stream>>>(W1, W3, W1T, W3T);
    dim3 gt2(DIM / 64, FF / 64, NE);
    tcvt_kernel<<<gt2, 256, 0, stream>>>(W2, W2T, FF, DIM);

    dim3 g1(FF / BN1, MAXT);
    gemm1f_kernel<<<g1, 256, 0, stream>>>(xb, W1T, W3T, pair_tok, seg, h);
    gemm2f_kernel<<<MAXT * 8 * KSPL, 256, 0, stream>>>(h, W2T, seg, y, y2);
    combine_kernel<<<N_TOK, 256, 0, stream>>>(y, y2, top_i, top_w, out);
}

// Round 8
// 482.891 us; speedup vs baseline: 1.2628x; 1.0895x over previous
//
#include <hip/hip_runtime.h>
#include <hip/hip_bf16.h>

// MoE SwiGLU FFN, top-2 of 8 experts. B=2,T=2048 -> N=4096 tokens, D=1024, F=4096.
//
//   router+tcvt13 : fused dispatch. bid<1024: router (4 tok/block, fp32 logits,
//                   top-2, softmax, x->bf16). bid>=1024: W1/W3 [E][D][F]->[E][F][D].
//   scan/build    : per-expert 128-row padded compaction; tok2row map
//   gemm1f+tcvtW2 : fused dispatch, grid y=328: y%4==0 && y/4<72 -> gemm1 tiles
//                   (proven 2-barrier 128x128 loop); other 256 rows -> W2 convert
//                   [E][F][D]->[E][D][F] overlapped under gemm1 compute.
//                   ROUND-7 BUG: grid y was 360 -> tr in [256,288) -> e=8 OOB
//                   (64MB past workspace) -> core dump. Fixed: y=328 + tr guard.
//   gemm2f        : y = h @ W2[e]  [BK=64 dbuf, counted-vmcnt, split-K=2]
//   combine       : out[tok] = w0*(y[r0]+y2[r0]) + w1*(y[r1]+y2[r1])
//
// NOTE (rounds 1/2/4/5): deep-pipeline gemm1 variants (BK=32 dbuf, counted-vmcnt
// 2-phase, 256-row 4-phase either prefetch placement) all REGRESSED
// (237/318/224/270 us vs 185). Do not retry without changing read:MFMA ratio.

typedef float f32x4 __attribute__((ext_vector_type(4)));
typedef __bf16 bf16x8 __attribute__((ext_vector_type(8)));

constexpr int N_TOK = 4096;
constexpr int DIM   = 1024;
constexpr int FF    = 4096;
constexpr int NE    = 8;
constexpr int TOPK  = 2;
constexpr int TILE_R = 128;
constexpr int MAXROWS = 9216;             // 8192 + 8*128 padding capacity
constexpr int MAXT    = MAXROWS / TILE_R; // 72

constexpr int BK  = 64;
constexpr int BN1 = 128;                  // gemm1 F-tile
constexpr int BN2 = 128;                  // gemm2 D-tile
constexpr int KSPL = 2;                   // gemm2 split-K

constexpr int TCVT2_ROWS = 256;           // W2 tcvt units / 32 x-blocks
constexpr int G1_YDIM = MAXT * 4 + (TCVT2_ROWS - MAXT * 3);   // 288 + 40 = 328

// ---- workspace offsets ----
constexpr size_t OFF_TOPI   = 0;          // top_i; rewritten by build -> tok2row
constexpr size_t OFF_TOPW   = 32768;
constexpr size_t OFF_CNT    = 65536;      // counts[8] @ +0, cursor[8] @ +128
constexpr size_t OFF_SEG    = 66048;
constexpr size_t OFF_PTOK   = 67072;
constexpr size_t OFF_XBF    = 140800;
constexpr size_t OFF_H      = OFF_XBF + (size_t)N_TOK * DIM * 2;
constexpr size_t OFF_W1T    = OFF_H   + (size_t)MAXROWS * FF * 2;
constexpr size_t OFF_W3T    = OFF_W1T + (size_t)NE * DIM * FF * 2;
constexpr size_t OFF_W2T    = OFF_W3T + (size_t)NE * DIM * FF * 2;
constexpr size_t OFF_Y      = OFF_W1T;    // y  [MAXROWS][DIM] f32 overlays W1T (dead after gemm1)
constexpr size_t OFF_Y2     = OFF_W3T;    // y2 [MAXROWS][DIM] f32 overlays W3T (dead after gemm1)

static __device__ __forceinline__ unsigned short f2bf(float f) {
    unsigned int x = __float_as_uint(f);
    x += 0x7FFFu + ((x >> 16) & 1u);    // round-to-nearest-even
    return (unsigned short)(x >> 16);
}

// async global->LDS, 16B per lane. LDS dest = wave-uniform base + lane*16 (linear);
// global src is per-lane (pre-swizzled for the XOR involution).
#define GLDS16(gsrc, ldst) \
    __builtin_amdgcn_global_load_lds( \
        (const __attribute__((address_space(1))) void*)(gsrc), \
        (__attribute__((address_space(3))) void*)(ldst), 16, 0, 0)

// raw barrier with compiler memory fences on both sides (no vmcnt drain)
static __device__ __forceinline__ void wg_barrier() {
    asm volatile("" ::: "memory");
    __builtin_amdgcn_s_barrier();
    asm volatile("" ::: "memory");
}

// shared 64x64 transpose-convert tile body (fp32 [R][C] tile -> bf16 [C][R])
static __device__ __forceinline__ void tcvt_tile(
    const float* __restrict__ s, unsigned short* __restrict__ d,
    int R, int C, int rt, int ct, unsigned short (*L)[65], int t)
{
    int r = t >> 4, c4 = (t & 15) * 4;
#pragma unroll
    for (int i = 0; i < 4; ++i) {
        float4 v = *(const float4*)(s + (size_t)(rt + r + i * 16) * C + ct + c4);
        L[r + i * 16][c4 + 0] = f2bf(v.x);
        L[r + i * 16][c4 + 1] = f2bf(v.y);
        L[r + i * 16][c4 + 2] = f2bf(v.z);
        L[r + i * 16][c4 + 3] = f2bf(v.w);
    }
    __syncthreads();
#pragma unroll
    for (int it = 0; it < 2; ++it) {
        int item = t + it * 256;
        int c  = item >> 3;
        int r8 = (item & 7) * 8;
        unsigned int w0 = (unsigned int)L[r8 + 0][c] | ((unsigned int)L[r8 + 1][c] << 16);
        unsigned int w1 = (unsigned int)L[r8 + 2][c] | ((unsigned int)L[r8 + 3][c] << 16);
        unsigned int w2 = (unsigned int)L[r8 + 4][c] | ((unsigned int)L[r8 + 5][c] << 16);
        unsigned int w3 = (unsigned int)L[r8 + 6][c] | ((unsigned int)L[r8 + 7][c] << 16);
        *(uint4*)(d + (size_t)(ct + c) * R + rt + r8) = make_uint4(w0, w1, w2, w3);
    }
}

// ---------------- fused: router (bid<1024) + W1/W3 transpose-convert ----------------
__global__ __launch_bounds__(256) void router_tcvt13_kernel(
    const float* __restrict__ x, const float* __restrict__ Wg,
    int* __restrict__ top_i, float* __restrict__ top_w, int* __restrict__ counts,
    unsigned short* __restrict__ xb,
    const float* __restrict__ W1f, const float* __restrict__ W3f,
    unsigned short* __restrict__ W1T, unsigned short* __restrict__ W3T)
{
    __shared__ unsigned short L[64][65];
    int bid = blockIdx.x;

    if (bid >= N_TOK / 4) {
        // tcvt role: 16384 blocks; W1 (z<8) / W3 (z>=8), [D][F] -> [F][D]
        int flat = bid - N_TOK / 4;
        int cx = flat & 63;                  // F/64
        int cy = (flat >> 6) & 15;           // D/64
        int z  = flat >> 10;                 // 0..15
        constexpr int R = DIM, C = FF;
        const float* s = ((z < NE) ? W1f : W3f) + (size_t)(z & 7) * R * C;
        unsigned short* d = ((z < NE) ? W1T : W3T) + (size_t)(z & 7) * R * C;
        tcvt_tile(s, d, R, C, cy * 64, cx * 64, L, threadIdx.x);
        return;
    }

    // router role: 4 tokens/block, 1 wave each
    int t = bid * 4 + (threadIdx.x >> 6);
    int lane = threadIdx.x & 63;
    float acc[NE];
#pragma unroll
    for (int e = 0; e < NE; ++e) acc[e] = 0.f;
    const float* xr = x + (size_t)t * DIM;
    unsigned short* xbr = xb + (size_t)t * DIM;
#pragma unroll
    for (int i = 0; i < DIM / 64; ++i) {
        int d = i * 64 + lane;
        float xv = xr[d];
        xbr[d] = f2bf(xv);
        const float4 w0 = *(const float4*)(Wg + (size_t)d * NE);
        const float4 w1 = *(const float4*)(Wg + (size_t)d * NE + 4);
        acc[0] += xv * w0.x; acc[1] += xv * w0.y; acc[2] += xv * w0.z; acc[3] += xv * w0.w;
        acc[4] += xv * w1.x; acc[5] += xv * w1.y; acc[6] += xv * w1.z; acc[7] += xv * w1.w;
    }
#pragma unroll
    for (int s = 32; s > 0; s >>= 1) {
#pragma unroll
        for (int e = 0; e < NE; ++e) acc[e] += __shfl_xor(acc[e], s);
    }
    if (lane == 0) {
        int i0 = 0; float v0 = acc[0];
#pragma unroll
        for (int e = 1; e < NE; ++e) if (acc[e] > v0) { v0 = acc[e]; i0 = e; }
        int i1 = -1; float v1 = -1e30f;
#pragma unroll
        for (int e = 0; e < NE; ++e) if (e != i0 && acc[e] > v1) { v1 = acc[e]; i1 = e; }
        float e1 = expf(v1 - v0);
        float inv = 1.f / (1.f + e1);
        top_i[t * 2 + 0] = i0;  top_i[t * 2 + 1] = i1;
        top_w[t * 2 + 0] = inv; top_w[t * 2 + 1] = e1 * inv;
        atomicAdd(&counts[i0], 1);
        atomicAdd(&counts[i1], 1);
    }
}

// ---------------- scan + tile descriptors ----------------
__global__ void scan_desc_kernel(const int* __restrict__ counts, int* __restrict__ seg)
{
    if (threadIdx.x != 0 || blockIdx.x != 0) return;
    int off = 0, nt = 0;
    for (int e = 0; e < NE; ++e) {
        seg[e] = off;
        int c = counts[e];
        int tiles = (c + TILE_R - 1) / TILE_R;
        for (int t = 0; t < tiles; ++t) {
            seg[16 + nt] = e;
            seg[96 + nt] = off + t * TILE_R;
            ++nt;
        }
        off += tiles * TILE_R;
    }
    seg[8] = nt;
}

// ---------------- build per-expert row lists; top_i becomes tok2row ----------------
__global__ __launch_bounds__(256) void build_kernel(
    int* __restrict__ top_i_rw,
    const int* __restrict__ seg, int* __restrict__ cursor,
    int* __restrict__ pair_tok)
{
    int idx = blockIdx.x * 256 + threadIdx.x;
    if (idx >= N_TOK * TOPK) return;
    int e = top_i_rw[idx];
    int pos = atomicAdd(&cursor[e], 1);
    int row = seg[e] + pos;
    pair_tok[row] = idx >> 1;
    top_i_rw[idx] = row;                  // tok2row (slot-private read-then-write)
}

// ---------------- fused: gemm1 (y%4==0, y/4<72) + W2 transpose-convert ----------------
// gemm1: proven single-buffer BK=64, 2 barriers/K-step, 128x128, 2x2 waves.
// tcvt role rows interleaved 3-per-gemm1-row (+40-row tail) so the BW-bound W2
// convert streams through free CU slots WHILE gemm1 computes (gemm2 launches
// after this kernel completes -> dependency safe).
__global__ __launch_bounds__(256, 2) void gemm1f_kernel(
    const unsigned short* __restrict__ xb, const unsigned short* __restrict__ W1T,
    const unsigned short* __restrict__ W3T,
    const int* __restrict__ pair_tok, const int* __restrict__ seg,
    unsigned short* __restrict__ h,
    const float* __restrict__ W2f, unsigned short* __restrict__ W2T)
{
    __shared__ __align__(16) char sm[49664];   // gemm1: As|B1s|B3s|toks ; tcvt: L[64][65]

    int yb = blockIdx.y;
    int q  = yb >> 2;
    bool isg = ((yb & 3) == 0) && (q < MAXT);

    if (!isg) {
        // tcvt role: 256 rows x 32 x-blocks = 8192 units; W2 [F][D] -> [D][F]
        int tr = (q < MAXT) ? (yb - q - 1) : (yb - MAXT);
        if (tr >= TCVT2_ROWS) return;        // guard (round-7 OOB bug)
        int flat = tr * 32 + blockIdx.x;
        int cx = flat & 15;                  // D/64
        int cy = (flat >> 4) & 63;           // F/64
        int e  = flat >> 10;                 // 0..7
        constexpr int R = FF, C = DIM;
        const float* s = W2f + (size_t)e * R * C;
        unsigned short* d = W2T + (size_t)e * R * C;
        tcvt_tile(s, d, R, C, cy * 64, cx * 64,
                  (unsigned short (*)[65])sm, threadIdx.x);
        return;
    }

    int tile = q;
    if (tile >= seg[8]) return;
    int e  = seg[16 + tile];
    int r0 = seg[96 + tile];
    int f0 = blockIdx.x * BN1;

    unsigned short* As  = (unsigned short*)sm;            // 16 KB
    unsigned short* B1s = (unsigned short*)(sm + 16384);  // 16 KB
    unsigned short* B3s = (unsigned short*)(sm + 32768);  // 16 KB
    int* toks = (int*)(sm + 49152);                       // 512 B

    int tid = threadIdx.x;
    if (tid < TILE_R) toks[tid] = pair_tok[r0 + tid];
    __syncthreads();

    int wid = tid >> 6, lane = tid & 63;
    int wm = wid >> 1, wn = wid & 1;             // 2x2 waves, each 64x64 per B
    int lrow = lane & 15;
    int lkb  = (lane >> 4) * 16;                 // frag k byte offset
    int axor = (lrow & 7) << 4;                  // read-side swizzle

    // pre-swizzled source col (elements) for glds staging:
    int sc = ((((lane & 7) * 16) ^ ((lane >> 3) << 4)) >> 1);

    const unsigned short* aSrc[4];
#pragma unroll
    for (int i = 0; i < 4; ++i) {
        int r = (wid * 4 + i) * 8 + (lane >> 3);
        int tok = toks[r]; if (tok < 0) tok = 0;   // pad rows: output discarded
        aSrc[i] = xb + (size_t)tok * DIM + sc;
    }
    const unsigned short *b1Src[4], *b3Src[4];
#pragma unroll
    for (int j = 0; j < 4; ++j) {
        int fl = (wid * 4 + j) * 8 + (lane >> 3);
        size_t rowoff = ((size_t)e * FF + f0 + fl) * DIM + sc;
        b1Src[j] = W1T + rowoff;
        b3Src[j] = W3T + rowoff;
    }

    f32x4 acc1[4][4], acc3[4][4];
    const f32x4 z4 = {0.f, 0.f, 0.f, 0.f};
#pragma unroll
    for (int m = 0; m < 4; ++m)
#pragma unroll
        for (int n = 0; n < 4; ++n) { acc1[m][n] = z4; acc3[m][n] = z4; }

    for (int k0 = 0; k0 < DIM; k0 += BK) {
#pragma unroll
        for (int i = 0; i < 4; ++i)
            GLDS16(aSrc[i] + k0, (char*)As + (wid * 4 + i) * 1024);
#pragma unroll
        for (int j = 0; j < 4; ++j) {
            GLDS16(b1Src[j] + k0, (char*)B1s + (wid * 4 + j) * 1024);
            GLDS16(b3Src[j] + k0, (char*)B3s + (wid * 4 + j) * 1024);
        }
        __syncthreads();   // drains vmcnt (glds) + barrier

#pragma unroll
        for (int kk = 0; kk < 2; ++kk) {
            int kb = kk * 64 + lkb;
            bf16x8 a[4], b1[4], b3[4];
#pragma unroll
            for (int m = 0; m < 4; ++m) {
                int row = wm * 64 + m * 16 + lrow;
                a[m] = *(const bf16x8*)((const char*)As + row * 128 + (kb ^ axor));
            }
#pragma unroll
            for (int n = 0; n < 4; ++n) {
                int row = wn * 64 + n * 16 + lrow;
                b1[n] = *(const bf16x8*)((const char*)B1s + row * 128 + (kb ^ axor));
                b3[n] = *(const bf16x8*)((const char*)B3s + row * 128 + (kb ^ axor));
            }
#pragma unroll
            for (int m = 0; m < 4; ++m)
#pragma unroll
                for (int n = 0; n < 4; ++n) {
                    acc1[m][n] = __builtin_amdgcn_mfma_f32_16x16x32_bf16(a[m], b1[n], acc1[m][n], 0, 0, 0);
                    acc3[m][n] = __builtin_amdgcn_mfma_f32_16x16x32_bf16(a[m], b3[n], acc3[m][n], 0, 0, 0);
                }
        }
        __syncthreads();
    }

    // epilogue: silu via v_rcp_f32 (1-ulp approx; absmax budget 6e-3)
    int lj = (lane >> 4) * 4;
#pragma unroll
    for (int m = 0; m < 4; ++m)
#pragma unroll
        for (int n = 0; n < 4; ++n)
#pragma unroll
            for (int j = 0; j < 4; ++j) {
                float h1 = acc1[m][n][j];
                float h3 = acc3[m][n][j];
                float s  = h1 * h3 * __builtin_amdgcn_rcpf(1.f + __expf(-h1));
                int row = r0 + wm * 64 + m * 16 + lj + j;
                int col = f0 + wn * 64 + n * 16 + lrow;
                h[(size_t)row * FF + col] = f2bf(s);
            }
}

// ---------------- gemm2: y(+y2) = h @ W2[e], 128x128, split-K=2, counted-vmcnt dbuf ----------------
// Grid 1152 = 2 khalf x (72 tiles x 8 dblk), XCD-chunked within each khalf.
// Each half reduces K/2=2048 and writes its own f32 partial (y / y2); combine sums.
__global__ __launch_bounds__(256, 2) void gemm2f_kernel(
    const unsigned short* __restrict__ h, const unsigned short* __restrict__ W2T,
    const int* __restrict__ seg, float* __restrict__ y, float* __restrict__ y2)
{
    int bid   = blockIdx.x;
    int khalf = bid / (MAXT * 8);
    int b2    = bid - khalf * (MAXT * 8);
    int x8   = b2 & 7;
    int dblk = (b2 >> 3) & 7;
    int t9   = (b2 >> 3) >> 3;
    int tile = x8 * (MAXT / 8) + t9;
    if (tile >= seg[8]) return;
    int e  = seg[16 + tile];
    int r0 = seg[96 + tile];
    int d0 = dblk * BN2;
    int kbase = khalf * (FF / KSPL);

    __shared__ __align__(16) char smem[2][32768];   // [buf][As 16KB | Bs 16KB]

    int tid = threadIdx.x;
    int wid = tid >> 6, lane = tid & 63;
    int wm = wid >> 1, wn = wid & 1;
    int lrow = lane & 15;
    int lkb  = (lane >> 4) * 16;
    int axor = (lrow & 7) << 4;
    int sc = ((((lane & 7) * 16) ^ ((lane >> 3) << 4)) >> 1);

    const unsigned short* aSrc[4];
#pragma unroll
    for (int i = 0; i < 4; ++i) {
        int r = (wid * 4 + i) * 8 + (lane >> 3);
        aSrc[i] = h + (size_t)(r0 + r) * FF + kbase + sc;
    }
    const unsigned short* bSrc[4];
#pragma unroll
    for (int j = 0; j < 4; ++j) {
        int dl = (wid * 4 + j) * 8 + (lane >> 3);
        bSrc[j] = W2T + ((size_t)e * DIM + d0 + dl) * FF + kbase + sc;
    }

#define STAGE2(buf, koff) { \
    char* AsB = smem[buf]; \
    char* BsB = smem[buf] + 16384; \
    _Pragma("unroll") \
    for (int i = 0; i < 4; ++i) \
        GLDS16(aSrc[i] + (koff), AsB + (wid * 4 + i) * 1024); \
    _Pragma("unroll") \
    for (int j = 0; j < 4; ++j) \
        GLDS16(bSrc[j] + (koff), BsB + (wid * 4 + j) * 1024); }

    f32x4 acc[4][4];
    const f32x4 z4 = {0.f, 0.f, 0.f, 0.f};
#pragma unroll
    for (int m = 0; m < 4; ++m)
#pragma unroll
        for (int n = 0; n < 4; ++n) acc[m][n] = z4;

    constexpr int NIT = (FF / KSPL) / BK;  // 32
    STAGE2(0, 0);
    int cur = 0;
    for (int it = 0; it < NIT; ++it) {
        if (it + 1 < NIT) {
            STAGE2(cur ^ 1, (it + 1) * BK);    // prefetch next K-step (8 loads)
            asm volatile("s_waitcnt vmcnt(8)" ::: "memory");  // cur staged; prefetch in flight
        } else {
            asm volatile("s_waitcnt vmcnt(0)" ::: "memory");
        }
        wg_barrier();                          // barrier 1: buf cur staged by ALL waves

        const char* AsR = smem[cur];
        const char* BsR = smem[cur] + 16384;
        bf16x8 a[2][4], b[2][4];
#pragma unroll
        for (int kk = 0; kk < 2; ++kk) {
            int kb = kk * 64 + lkb;
#pragma unroll
            for (int m = 0; m < 4; ++m) {
                int row = wm * 64 + m * 16 + lrow;
                a[kk][m] = *(const bf16x8*)(AsR + row * 128 + (kb ^ axor));
            }
#pragma unroll
            for (int n = 0; n < 4; ++n) {
                int row = wn * 64 + n * 16 + lrow;
                b[kk][n] = *(const bf16x8*)(BsR + row * 128 + (kb ^ axor));
            }
        }
        asm volatile("s_waitcnt lgkmcnt(0)" ::: "memory");
        wg_barrier();                          // barrier 2: reads retired; cur overwritable

#pragma unroll
        for (int kk = 0; kk < 2; ++kk)
#pragma unroll
            for (int m = 0; m < 4; ++m)
#pragma unroll
                for (int n = 0; n < 4; ++n)
                    acc[m][n] = __builtin_amdgcn_mfma_f32_16x16x32_bf16(a[kk][m], b[kk][n], acc[m][n], 0, 0, 0);
        cur ^= 1;
    }
#undef STAGE2

    // epilogue: direct scattered f32 stores (64B per 16-lane group)
    float* yt = khalf ? y2 : y;
    int lj = (lane >> 4) * 4;
#pragma unroll
    for (int m = 0; m < 4; ++m)
#pragma unroll
        for (int n = 0; n < 4; ++n)
#pragma unroll
            for (int j = 0; j < 4; ++j) {
                int row = r0 + wm * 64 + m * 16 + lj + j;     // pad rows: never combined
                int col = d0 + wn * 64 + n * 16 + lrow;
                yt[(size_t)row * DIM + col] = acc[m][n][j];
            }
}

// ---------------- combine: out[tok] = w0*(y[r0]+y2[r0]) + w1*(y[r1]+y2[r1]) ----------------
__global__ __launch_bounds__(256) void combine_kernel(
    const float* __restrict__ y, const float* __restrict__ y2,
    const int* __restrict__ tok2row,
    const float* __restrict__ top_w, float* __restrict__ out)
{
    int t = blockIdx.x;
    int c = threadIdx.x * 4;
    int r0 = tok2row[t * 2], r1 = tok2row[t * 2 + 1];
    float w0 = top_w[t * 2], w1 = top_w[t * 2 + 1];
    float4 a0 = *(const float4*)(y  + (size_t)r0 * DIM + c);
    float4 a1 = *(const float4*)(y2 + (size_t)r0 * DIM + c);
    float4 b0 = *(const float4*)(y  + (size_t)r1 * DIM + c);
    float4 b1 = *(const float4*)(y2 + (size_t)r1 * DIM + c);
    float4 o;
    o.x = w0 * (a0.x + a1.x) + w1 * (b0.x + b1.x);
    o.y = w0 * (a0.y + a1.y) + w1 * (b0.y + b1.y);
    o.z = w0 * (a0.z + a1.z) + w1 * (b0.z + b1.z);
    o.w = w0 * (a0.w + a1.w) + w1 * (b0.w + b1.w);
    *(float4*)(out + (size_t)t * DIM + c) = o;
}

extern "C" void kernel_launch(void* const* d_in, const int* in_sizes, int n_in,
                              void* d_out, int out_size, void* d_ws, size_t ws_size,
                              hipStream_t stream)
{
    const float* x  = (const float*)d_in[0];
    const float* Wg = (const float*)d_in[1];
    const float* W1 = (const float*)d_in[2];
    const float* W3 = (const float*)d_in[3];
    const float* W2 = (const float*)d_in[4];
    float* out = (float*)d_out;

    char* ws = (char*)d_ws;
    int*   top_i    = (int*)(ws + OFF_TOPI);   // becomes tok2row after build
    float* top_w    = (float*)(ws + OFF_TOPW);
    int*   counts   = (int*)(ws + OFF_CNT);
    int*   cursor   = (int*)(ws + OFF_CNT + 128);
    int*   seg      = (int*)(ws + OFF_SEG);
    int*   pair_tok = (int*)(ws + OFF_PTOK);
    unsigned short* xb  = (unsigned short*)(ws + OFF_XBF);
    unsigned short* h   = (unsigned short*)(ws + OFF_H);
    unsigned short* W1T = (unsigned short*)(ws + OFF_W1T);
    unsigned short* W3T = (unsigned short*)(ws + OFF_W3T);
    unsigned short* W2T = (unsigned short*)(ws + OFF_W2T);
    float* y  = (float*)(ws + OFF_Y);
    float* y2 = (float*)(ws + OFF_Y2);

    hipMemsetAsync(counts, 0, 512, stream);
    hipMemsetAsync(pair_tok, 0xFF, MAXROWS * sizeof(int), stream);

    // fused router + W1/W3 convert: 1024 router blocks + 16384 tcvt blocks
    router_tcvt13_kernel<<<N_TOK / 4 + 16384, 256, 0, stream>>>(
        x, Wg, top_i, top_w, counts, xb, W1, W3, W1T, W3T);
    scan_desc_kernel<<<1, 64, 0, stream>>>(counts, seg);
    build_kernel<<<(N_TOK * TOPK + 255) / 256, 256, 0, stream>>>(top_i, seg, cursor, pair_tok);

    // fused gemm1 + W2 convert: 72 gemm1 y-rows + 256 tcvt y-rows = 328
    dim3 g1(FF / BN1, G1_YDIM);
    gemm1f_kernel<<<g1, 256, 0, stream>>>(xb, W1T, W3T, pair_tok, seg, h, W2, W2T);
    gemm2f_kernel<<<MAXT * 8 * KSPL, 256, 0, stream>>>(h, W2T, seg, y, y2);
    combine_kernel<<<N_TOK, 256, 0, stream>>>(y, y2, top_i, top_w, out);
}